// Round 1
// baseline (427.339 us; speedup 1.0000x reference)
//
#include <hip/hip_runtime.h>

#define NTOK 4096          // B*N
#define AST  264           // LDS A-tile row stride in shorts (bank-conflict pad)

using short8  = __attribute__((ext_vector_type(8))) short;
using short4v = __attribute__((ext_vector_type(4))) short;
using floatx4 = __attribute__((ext_vector_type(4))) float;

static __device__ __forceinline__ float bf2f(short s) {
  union { unsigned u; float f; } v; v.u = ((unsigned)(unsigned short)s) << 16;
  return v.f;
}

// Packed f32x2 -> bf16x2 RNE conversion: 1 instr replaces ~10 of bit-twiddle+pack.
static __device__ __forceinline__ unsigned cvt_pk_bf16(float lo, float hi) {
  unsigned d;
  asm("v_cvt_pk_bf16_f32 %0, %1, %2" : "=v"(d) : "v"(lo), "v"(hi));
  return d;
}

// Branchless GELU via erf, Abramowitz-Stegun 7.1.25 (3-term, |eps|<=2.5e-5).
// erf error is ~150x below the bf16 input quantization already in the pipeline.
static __device__ __forceinline__ float fast_gelu(float z) {
  float x  = z * 0.70710678118654752f;
  float ax = fabsf(x);
  float t  = __builtin_amdgcn_rcpf(fmaf(0.47047f, ax, 1.0f));
  float em = __expf(-ax * ax);
  float p  = fmaf(fmaf(0.7478556f, t, -0.0958798f), t, 0.3480242f);
  float er = fmaf(-(p * t), em, 1.0f);               // erf(|x|) in [0,1)
  unsigned sgn = __float_as_uint(x) & 0x80000000u;
  er = __uint_as_float(__float_as_uint(er) | sgn);   // copysign
  return z * fmaf(0.5f, er, 0.5f);
}

// Coalesced pre-swizzle of W1[0:256,0:256] into bf16 B-fragment order:
// W1s[((s*16 + t)*64 + l)*8 + j] = bf16(W1[k*256 + n]),
//   k = s*32 + (l>>4)*8 + j, n = t*16 + (l&15).
__global__ void prep_w1(const float* __restrict__ W1, short* __restrict__ W1s) {
  const int n  = threadIdx.x;     // 0..255
  const int kb = blockIdx.x;      // 0..31
  const int s  = kb >> 2;
  const int l  = ((kb & 3) << 4) | (n & 15);
  const int t  = n >> 4;
  float f[8];
  #pragma unroll
  for (int j = 0; j < 8; ++j) f[j] = W1[(kb * 8 + j) * 256 + n];
  uint4 u;
  u.x = cvt_pk_bf16(f[0], f[1]);
  u.y = cvt_pk_bf16(f[2], f[3]);
  u.z = cvt_pk_bf16(f[4], f[5]);
  u.w = cvt_pk_bf16(f[6], f[7]);
  *(uint4*)(W1s + (((s * 16 + t) * 64 + l) << 3)) = u;
}

__global__ void __launch_bounds__(256, 4) agg_kernel(
    const float* __restrict__ sampled, const float* __restrict__ valid,
    const float* __restrict__ y_norm, const float* __restrict__ W1,
    const float* __restrict__ b1, const float* __restrict__ W2,
    const float* __restrict__ b2, const short* __restrict__ W1s,
    float* __restrict__ out) {
  __shared__ __align__(16) short Abf[64 * AST];   // 33,792 B bf16 A tile
  __shared__ float wlog[4][64];                   // per-wave partial logits
  __shared__ float ynl[64];                       // y_norm

  const int tid = threadIdx.x;
  const int tok = blockIdx.x;
  const float* S = sampled + ((size_t)tok << 14);   // 64*256 floats per token

  // ---- phase 0: stage sampled tile to LDS as bf16 (8-deep load pipeline) ----
  if (tid < 64) ynl[tid] = y_norm[tid];
  const float4* S4 = (const float4*)S;
  #pragma unroll
  for (int h = 0; h < 2; ++h) {
    float4 v[8];
    #pragma unroll
    for (int it = 0; it < 8; ++it) v[it] = S4[(h * 8 + it) * 256 + tid];
    #pragma unroll
    for (int it = 0; it < 8; ++it) {
      int j  = (h * 8 + it) * 256 + tid;
      int y  = j >> 6;
      int k4 = (j & 63) << 2;
      uint2 dd;
      dd.x = cvt_pk_bf16(v[it].x, v[it].y);
      dd.y = cvt_pk_bf16(v[it].z, v[it].w);
      *(uint2*)(&Abf[y * AST + k4]) = dd;           // ds_write_b64
    }
  }
  __syncthreads();

  // ---- phase 1: GEMM  z[64x256] = A(bf16) * W1[0:256](bf16), fp32 acc ----
  const int wv  = tid >> 6;        // wave 0..3 -> owns n in [64*wv, 64*wv+64)
  const int ln  = tid & 63;
  const int q   = ln >> 4;
  const int c15 = ln & 15;

  const floatx4 fzero = {0.f, 0.f, 0.f, 0.f};
  floatx4 acc[4][4];
  #pragma unroll
  for (int mt = 0; mt < 4; ++mt)
    #pragma unroll
    for (int nt = 0; nt < 4; ++nt) acc[mt][nt] = fzero;

  #pragma unroll
  for (int s = 0; s < 8; ++s) {
    short8 af[4];
    #pragma unroll
    for (int mt = 0; mt < 4; ++mt)
      af[mt] = *(const short8*)(&Abf[(mt * 16 + c15) * AST + s * 32 + q * 8]);
    #pragma unroll
    for (int nt = 0; nt < 4; ++nt) {
      const int t = wv * 4 + nt;
      short8 bfrag = *(const short8*)(W1s + (((s * 16 + t) * 64 + ln) << 3));
      #pragma unroll
      for (int mt = 0; mt < 4; ++mt)
        acc[mt][nt] = __builtin_amdgcn_mfma_f32_16x16x32_bf16(af[mt], bfrag, acc[mt][nt], 0, 0, 0);
    }
  }

  // ---- phase 2: epilogue  h = gelu(z + y*W1_last + b1); partial logits = h.W2 ----
  float w2v[4], b1v[4], wlv[4];
  #pragma unroll
  for (int nt = 0; nt < 4; ++nt) {
    int n = wv * 64 + nt * 16 + c15;
    w2v[nt] = W2[n];
    b1v[nt] = b1[n];
    wlv[nt] = W1[65536 + n];        // W1[256][n] — the y-feature row
  }
  #pragma unroll
  for (int mt = 0; mt < 4; ++mt) {
    #pragma unroll
    for (int r = 0; r < 4; ++r) {
      int m = mt * 16 + q * 4 + r;    // D row = quad*4 + reg
      float ym = ynl[m];
      float p = 0.f;
      #pragma unroll
      for (int nt = 0; nt < 4; ++nt) {
        float z = acc[mt][nt][r] + ym * wlv[nt] + b1v[nt];
        p += fast_gelu(z) * w2v[nt];
      }
      // reduce over the 16 cols held by lanes c15=0..15
      p += __shfl_xor(p, 1);
      p += __shfl_xor(p, 2);
      p += __shfl_xor(p, 4);
      p += __shfl_xor(p, 8);
      if (c15 == 0) wlog[wv][m] = p;
    }
  }
  __syncthreads();

  // ---- phase 3: masked softmax over Y=64, redundantly in every wave ----
  float lg = wlog[0][ln] + wlog[1][ln] + wlog[2][ln] + wlog[3][ln] + b2[0];
  float vv = valid[tok * 64 + ln];
  float lm = (vv < 0.5f) ? -10000.0f : lg;
  float mx = lm;
  #pragma unroll
  for (int d = 32; d > 0; d >>= 1) mx = fmaxf(mx, __shfl_xor(mx, d));
  float e  = __expf(lm - mx);
  float s1 = e;
  #pragma unroll
  for (int d = 32; d > 0; d >>= 1) s1 += __shfl_xor(s1, d);
  float wgt = e / s1 * vv;
  float s2  = wgt;
  #pragma unroll
  for (int d = 32; d > 0; d >>= 1) s2 += __shfl_xor(s2, d);
  wgt = wgt / fmaxf(s2, 1e-6f);     // lane ln holds weight for y=ln

  // ---- phase 4: out[c] = sum_y A_bf16[y][c] * w[y]  (LDS reads, no barrier) ----
  float a0 = 0.f;
  #pragma unroll
  for (int y = 0; y < 64; ++y) {
    float wy = __shfl(wgt, y);      // compile-time lane -> v_readlane (SGPR)
    a0 = fmaf(bf2f(Abf[y * AST + tid]), wy, a0);
  }
  out[(size_t)tok * 256 + tid] = a0;
}

extern "C" void kernel_launch(void* const* d_in, const int* in_sizes, int n_in,
                              void* d_out, int out_size, void* d_ws, size_t ws_size,
                              hipStream_t stream) {
  const float* sampled = (const float*)d_in[0];
  const float* valid   = (const float*)d_in[1];
  const float* y_norm  = (const float*)d_in[2];
  const float* W1      = (const float*)d_in[3];   // [257,256]
  const float* b1      = (const float*)d_in[4];
  const float* W2      = (const float*)d_in[5];
  const float* b2      = (const float*)d_in[6];
  short* W1s = (short*)d_ws;                      // 128 KiB swizzled bf16 W1
  float* out = (float*)d_out;

  prep_w1<<<32, 256, 0, stream>>>(W1, W1s);
  agg_kernel<<<NTOK, 256, 0, stream>>>(sampled, valid, y_norm, W1, b1, W2, b2, W1s, out);
}

// Round 2
// 420.790 us; speedup vs baseline: 1.0156x; 1.0156x over previous
//
#include <hip/hip_runtime.h>

#define NTOK 4096          // B*N
#define AST  264           // LDS A-tile row stride in shorts (bank-conflict pad)

using short8  = __attribute__((ext_vector_type(8))) short;
using floatx4 = __attribute__((ext_vector_type(4))) float;

static __device__ __forceinline__ float bf2f(short s) {
  union { unsigned u; float f; } v; v.u = ((unsigned)(unsigned short)s) << 16;
  return v.f;
}

// Packed f32x2 -> bf16x2 RNE conversion: 1 instr replaces ~10 of bit-twiddle+pack.
static __device__ __forceinline__ unsigned cvt_pk_bf16(float lo, float hi) {
  unsigned d;
  asm("v_cvt_pk_bf16_f32 %0, %1, %2" : "=v"(d) : "v"(lo), "v"(hi));
  return d;
}

// Branchless GELU via erf, Abramowitz-Stegun 7.1.25 (3-term, |eps|<=2.5e-5).
static __device__ __forceinline__ float fast_gelu(float z) {
  float x  = z * 0.70710678118654752f;
  float ax = fabsf(x);
  float t  = __builtin_amdgcn_rcpf(fmaf(0.47047f, ax, 1.0f));
  float em = __expf(-ax * ax);
  float p  = fmaf(fmaf(0.7478556f, t, -0.0958798f), t, 0.3480242f);
  float er = fmaf(-(p * t), em, 1.0f);               // erf(|x|) in [0,1)
  unsigned sgn = __float_as_uint(x) & 0x80000000u;
  er = __uint_as_float(__float_as_uint(er) | sgn);   // copysign
  return z * fmaf(0.5f, er, 0.5f);
}

// Coalesced pre-swizzle of W1[0:256,0:256] into bf16 B-fragment order:
// W1s[((s*16 + t)*64 + l)*8 + j] = bf16(W1[k*256 + n]),
//   k = s*32 + (l>>4)*8 + j, n = t*16 + (l&15).
__global__ void prep_w1(const float* __restrict__ W1, short* __restrict__ W1s) {
  const int n  = threadIdx.x;     // 0..255
  const int kb = blockIdx.x;      // 0..31
  const int s  = kb >> 2;
  const int l  = ((kb & 3) << 4) | (n & 15);
  const int t  = n >> 4;
  float f[8];
  #pragma unroll
  for (int j = 0; j < 8; ++j) f[j] = W1[(kb * 8 + j) * 256 + n];
  uint4 u;
  u.x = cvt_pk_bf16(f[0], f[1]);
  u.y = cvt_pk_bf16(f[2], f[3]);
  u.z = cvt_pk_bf16(f[4], f[5]);
  u.w = cvt_pk_bf16(f[6], f[7]);
  *(uint4*)(W1s + (((s * 16 + t) * 64 + l) << 3)) = u;
}

// 512 threads / 8 waves per block; each wave owns 32 output columns.
// Halves per-wave acc (32 AGPR), W1s loads, and gelu work vs the 4-wave
// version -> latency gaps shrink AND 24 waves/CU (vs 16) hide them.
// __launch_bounds__(512,6): 6 waves/EU = 3 blocks/CU, reg cap ~85.
__global__ void __launch_bounds__(512, 6) agg_kernel(
    const float* __restrict__ sampled, const float* __restrict__ valid,
    const float* __restrict__ y_norm, const float* __restrict__ W1,
    const float* __restrict__ b1, const float* __restrict__ W2,
    const float* __restrict__ b2, const short* __restrict__ W1s,
    float* __restrict__ out) {
  __shared__ __align__(16) short Abf[64 * AST];   // 33,792 B bf16 A tile
  __shared__ float wlog[8][64];                   // per-wave partial logits
  __shared__ float ynl[64];                       // y_norm
  __shared__ float ph[256];                       // phase-4 half-sum exchange

  const int tid = threadIdx.x;
  const int tok = blockIdx.x;
  const float* S = sampled + ((size_t)tok << 14);   // 64*256 floats per token

  // ---- phase 0: stage sampled tile to LDS as bf16 (8 float4 per thread) ----
  if (tid < 64) ynl[tid] = y_norm[tid];
  const float4* S4 = (const float4*)S;
  float4 v[8];
  #pragma unroll
  for (int it = 0; it < 8; ++it) v[it] = S4[it * 512 + tid];
  #pragma unroll
  for (int it = 0; it < 8; ++it) {
    int j  = it * 512 + tid;        // float4 index in [0,4096)
    int y  = j >> 6;
    int k4 = (j & 63) << 2;
    uint2 dd;
    dd.x = cvt_pk_bf16(v[it].x, v[it].y);
    dd.y = cvt_pk_bf16(v[it].z, v[it].w);
    *(uint2*)(&Abf[y * AST + k4]) = dd;           // ds_write_b64
  }
  __syncthreads();

  // ---- phase 1: GEMM  z[64x256] = A(bf16) * W1[0:256](bf16), fp32 acc ----
  const int wv  = tid >> 6;        // wave 0..7 -> owns n in [32*wv, 32*wv+32)
  const int ln  = tid & 63;
  const int q   = ln >> 4;
  const int c15 = ln & 15;

  const floatx4 fzero = {0.f, 0.f, 0.f, 0.f};
  floatx4 acc[4][2];
  #pragma unroll
  for (int mt = 0; mt < 4; ++mt)
    #pragma unroll
    for (int nt = 0; nt < 2; ++nt) acc[mt][nt] = fzero;

  #pragma unroll
  for (int s = 0; s < 8; ++s) {
    short8 af[4];
    #pragma unroll
    for (int mt = 0; mt < 4; ++mt)
      af[mt] = *(const short8*)(&Abf[(mt * 16 + c15) * AST + s * 32 + q * 8]);
    #pragma unroll
    for (int nt = 0; nt < 2; ++nt) {
      const int t = wv * 2 + nt;
      short8 bfrag = *(const short8*)(W1s + (((s * 16 + t) * 64 + ln) << 3));
      #pragma unroll
      for (int mt = 0; mt < 4; ++mt)
        acc[mt][nt] = __builtin_amdgcn_mfma_f32_16x16x32_bf16(af[mt], bfrag, acc[mt][nt], 0, 0, 0);
    }
  }

  // ---- phase 2: epilogue  h = gelu(z + y*W1_last + b1); partial logits = h.W2 ----
  float w2v[2], b1v[2], wlv[2];
  #pragma unroll
  for (int nt = 0; nt < 2; ++nt) {
    int n = wv * 32 + nt * 16 + c15;
    w2v[nt] = W2[n];
    b1v[nt] = b1[n];
    wlv[nt] = W1[65536 + n];        // W1[256][n] — the y-feature row
  }
  #pragma unroll
  for (int mt = 0; mt < 4; ++mt) {
    #pragma unroll
    for (int r = 0; r < 4; ++r) {
      int m = mt * 16 + q * 4 + r;    // D row = quad*4 + reg
      float ym = ynl[m];
      float p = 0.f;
      #pragma unroll
      for (int nt = 0; nt < 2; ++nt) {
        float z = acc[mt][nt][r] + ym * wlv[nt] + b1v[nt];
        p += fast_gelu(z) * w2v[nt];
      }
      // reduce over the 16 cols held by lanes c15=0..15
      p += __shfl_xor(p, 1);
      p += __shfl_xor(p, 2);
      p += __shfl_xor(p, 4);
      p += __shfl_xor(p, 8);
      if (c15 == 0) wlog[wv][m] = p;
    }
  }
  __syncthreads();

  // ---- phase 3: masked softmax over Y=64, redundantly in every wave ----
  float lg = ((wlog[0][ln] + wlog[1][ln]) + (wlog[2][ln] + wlog[3][ln]))
           + ((wlog[4][ln] + wlog[5][ln]) + (wlog[6][ln] + wlog[7][ln])) + b2[0];
  float vv = valid[tok * 64 + ln];
  float lm = (vv < 0.5f) ? -10000.0f : lg;
  float mx = lm;
  #pragma unroll
  for (int d = 32; d > 0; d >>= 1) mx = fmaxf(mx, __shfl_xor(mx, d));
  float e  = __expf(lm - mx);
  float s1 = e;
  #pragma unroll
  for (int d = 32; d > 0; d >>= 1) s1 += __shfl_xor(s1, d);
  float wgt = e / s1 * vv;
  float s2  = wgt;
  #pragma unroll
  for (int d = 32; d > 0; d >>= 1) s2 += __shfl_xor(s2, d);
  wgt = wgt / fmaxf(s2, 1e-6f);     // lane ln holds weight for y=ln

  // ---- phase 4: out[c] = sum_y A_bf16[y][c] * w[y], split across halves ----
  float a0 = 0.f;
  if (tid < 256) {
    #pragma unroll
    for (int y = 0; y < 32; ++y) {
      float wy = __shfl(wgt, y);    // literal lane -> v_readlane (SGPR)
      a0 = fmaf(bf2f(Abf[y * AST + tid]), wy, a0);
    }
  } else {
    const int c = tid - 256;
    #pragma unroll
    for (int y = 32; y < 64; ++y) {
      float wy = __shfl(wgt, y);
      a0 = fmaf(bf2f(Abf[y * AST + c]), wy, a0);
    }
    ph[c] = a0;
  }
  __syncthreads();
  if (tid < 256) out[(size_t)tok * 256 + tid] = a0 + ph[tid];
}

extern "C" void kernel_launch(void* const* d_in, const int* in_sizes, int n_in,
                              void* d_out, int out_size, void* d_ws, size_t ws_size,
                              hipStream_t stream) {
  const float* sampled = (const float*)d_in[0];
  const float* valid   = (const float*)d_in[1];
  const float* y_norm  = (const float*)d_in[2];
  const float* W1      = (const float*)d_in[3];   // [257,256]
  const float* b1      = (const float*)d_in[4];
  const float* W2      = (const float*)d_in[5];
  const float* b2      = (const float*)d_in[6];
  short* W1s = (short*)d_ws;                      // 128 KiB swizzled bf16 W1
  float* out = (float*)d_out;

  prep_w1<<<32, 256, 0, stream>>>(W1, W1s);
  agg_kernel<<<NTOK, 512, 0, stream>>>(sampled, valid, y_norm, W1, b1, W2, b2, W1s, out);
}

// Round 3
// 400.521 us; speedup vs baseline: 1.0670x; 1.0506x over previous
//
#include <hip/hip_runtime.h>

#define NTOK 4096          // B*N
#define AST  264           // LDS A-tile row stride in shorts (bank-conflict pad)

using short8  = __attribute__((ext_vector_type(8))) short;
using floatx4 = __attribute__((ext_vector_type(4))) float;

static __device__ __forceinline__ float bf2f(short s) {
  union { unsigned u; float f; } v; v.u = ((unsigned)(unsigned short)s) << 16;
  return v.f;
}

// Packed f32x2 -> bf16x2 RNE conversion (single instr).
static __device__ __forceinline__ unsigned cvt_pk_bf16(float lo, float hi) {
  unsigned d;
  asm("v_cvt_pk_bf16_f32 %0, %1, %2" : "=v"(d) : "v"(lo), "v"(hi));
  return d;
}

// Branchless GELU via erf, Abramowitz-Stegun 7.1.25 (3-term, |eps|<=2.5e-5).
static __device__ __forceinline__ float fast_gelu(float z) {
  float x  = z * 0.70710678118654752f;
  float ax = fabsf(x);
  float t  = __builtin_amdgcn_rcpf(fmaf(0.47047f, ax, 1.0f));
  float em = __expf(-ax * ax);
  float p  = fmaf(fmaf(0.7478556f, t, -0.0958798f), t, 0.3480242f);
  float er = fmaf(-(p * t), em, 1.0f);               // erf(|x|) in [0,1)
  unsigned sgn = __float_as_uint(x) & 0x80000000u;
  er = __uint_as_float(__float_as_uint(er) | sgn);   // copysign
  return z * fmaf(0.5f, er, 0.5f);
}

// Coalesced pre-swizzle of W1[0:256,0:256] into bf16 B-fragment order:
// W1s[((s*16 + t)*64 + l)*8 + j] = bf16(W1[k*256 + n]),
//   k = s*32 + (l>>4)*8 + j, n = t*16 + (l&15).
__global__ void prep_w1(const float* __restrict__ W1, short* __restrict__ W1s) {
  const int n  = threadIdx.x;     // 0..255
  const int kb = blockIdx.x;      // 0..31
  const int s  = kb >> 2;
  const int l  = ((kb & 3) << 4) | (n & 15);
  const int t  = n >> 4;
  float f[8];
  #pragma unroll
  for (int j = 0; j < 8; ++j) f[j] = W1[(kb * 8 + j) * 256 + n];
  uint4 u;
  u.x = cvt_pk_bf16(f[0], f[1]);
  u.y = cvt_pk_bf16(f[2], f[3]);
  u.z = cvt_pk_bf16(f[4], f[5]);
  u.w = cvt_pk_bf16(f[6], f[7]);
  *(uint4*)(W1s + (((s * 16 + t) * 64 + l) << 3)) = u;
}

// 512 threads / 8 waves; each wave owns 32 output columns.
// KEY CHANGE vs r2: __launch_bounds__(512,4) -> 128-reg cap (was 40!), and
// each wave PRELOADS its whole W1s slice (16 x short8 = 64 VGPR) into
// registers concurrently with the 8 A-tile float4 loads. All 24 global
// loads per thread are in flight at once (FIFO vmcnt drains A first);
// the GEMM loop has zero global loads -> no serialized L2 latency.
__global__ void __launch_bounds__(512, 4) agg_kernel(
    const float* __restrict__ sampled, const float* __restrict__ valid,
    const float* __restrict__ y_norm, const float* __restrict__ W1,
    const float* __restrict__ b1, const float* __restrict__ W2,
    const float* __restrict__ b2, const short* __restrict__ W1s,
    float* __restrict__ out) {
  __shared__ __align__(16) short Abf[64 * AST];   // 33,792 B bf16 A tile
  __shared__ float wlog[8][64];                   // per-wave partial logits
  __shared__ float ynl[64];                       // y_norm
  __shared__ float ph[256];                       // phase-4 half-sum exchange

  const int tid = threadIdx.x;
  const int tok = blockIdx.x;
  const int wv  = tid >> 6;        // wave 0..7 -> owns n in [32*wv, 32*wv+32)
  const int ln  = tid & 63;
  const int q   = ln >> 4;
  const int c15 = ln & 15;
  const float* S = sampled + ((size_t)tok << 14);   // 64*256 floats per token

  if (tid < 64) ynl[tid] = y_norm[tid];

  // ---- phase 0a: issue 8 A-tile float4 loads (oldest in vmcnt FIFO) ----
  const float4* S4 = (const float4*)S;
  float4 v[8];
  #pragma unroll
  for (int it = 0; it < 8; ++it) v[it] = S4[it * 512 + tid];

  // ---- phase 0b: issue this wave's W1s slice, 16 x b128 -> registers ----
  short8 bfr[16];
  #pragma unroll
  for (int s = 0; s < 8; ++s)
    #pragma unroll
    for (int nt = 0; nt < 2; ++nt)
      bfr[s * 2 + nt] =
          *(const short8*)(W1s + (((s * 16 + wv * 2 + nt) * 64 + ln) << 3));

  // ---- phase 0c: convert A to bf16, write LDS (drains A loads in order) ----
  #pragma unroll
  for (int it = 0; it < 8; ++it) {
    int j  = it * 512 + tid;        // float4 index in [0,4096)
    int y  = j >> 6;
    int k4 = (j & 63) << 2;
    uint2 dd;
    dd.x = cvt_pk_bf16(v[it].x, v[it].y);
    dd.y = cvt_pk_bf16(v[it].z, v[it].w);
    *(uint2*)(&Abf[y * AST + k4]) = dd;           // ds_write_b64
  }
  __syncthreads();

  // ---- phase 1: GEMM z[64x256] = A(bf16)*W1(bf16); B-frags all in regs ----
  const floatx4 fzero = {0.f, 0.f, 0.f, 0.f};
  floatx4 acc[4][2];
  #pragma unroll
  for (int mt = 0; mt < 4; ++mt)
    #pragma unroll
    for (int nt = 0; nt < 2; ++nt) acc[mt][nt] = fzero;

  #pragma unroll
  for (int s = 0; s < 8; ++s) {
    short8 af[4];
    #pragma unroll
    for (int mt = 0; mt < 4; ++mt)
      af[mt] = *(const short8*)(&Abf[(mt * 16 + c15) * AST + s * 32 + q * 8]);
    #pragma unroll
    for (int nt = 0; nt < 2; ++nt)
      #pragma unroll
      for (int mt = 0; mt < 4; ++mt)
        acc[mt][nt] = __builtin_amdgcn_mfma_f32_16x16x32_bf16(
            af[mt], bfr[s * 2 + nt], acc[mt][nt], 0, 0, 0);
  }

  // ---- phase 2: epilogue h = gelu(z + y*W1_last + b1); partial logits ----
  float w2v[2], b1v[2], wlv[2];
  #pragma unroll
  for (int nt = 0; nt < 2; ++nt) {
    int n = wv * 32 + nt * 16 + c15;
    w2v[nt] = W2[n];
    b1v[nt] = b1[n];
    wlv[nt] = W1[65536 + n];        // W1[256][n] — the y-feature row
  }
  #pragma unroll
  for (int mt = 0; mt < 4; ++mt) {
    #pragma unroll
    for (int r = 0; r < 4; ++r) {
      int m = mt * 16 + q * 4 + r;    // D row = quad*4 + reg
      float ym = ynl[m];
      float p = 0.f;
      #pragma unroll
      for (int nt = 0; nt < 2; ++nt) {
        float z = acc[mt][nt][r] + ym * wlv[nt] + b1v[nt];
        p += fast_gelu(z) * w2v[nt];
      }
      // reduce over the 16 cols held by lanes c15=0..15
      p += __shfl_xor(p, 1);
      p += __shfl_xor(p, 2);
      p += __shfl_xor(p, 4);
      p += __shfl_xor(p, 8);
      if (c15 == 0) wlog[wv][m] = p;
    }
  }
  __syncthreads();

  // ---- phase 3: masked softmax over Y=64, redundantly in every wave ----
  float lg = ((wlog[0][ln] + wlog[1][ln]) + (wlog[2][ln] + wlog[3][ln]))
           + ((wlog[4][ln] + wlog[5][ln]) + (wlog[6][ln] + wlog[7][ln])) + b2[0];
  float vv = valid[tok * 64 + ln];
  float lm = (vv < 0.5f) ? -10000.0f : lg;
  float mx = lm;
  #pragma unroll
  for (int d = 32; d > 0; d >>= 1) mx = fmaxf(mx, __shfl_xor(mx, d));
  float e  = __expf(lm - mx);
  float s1 = e;
  #pragma unroll
  for (int d = 32; d > 0; d >>= 1) s1 += __shfl_xor(s1, d);
  float wgt = e / s1 * vv;
  float s2  = wgt;
  #pragma unroll
  for (int d = 32; d > 0; d >>= 1) s2 += __shfl_xor(s2, d);
  wgt = wgt / fmaxf(s2, 1e-6f);     // lane ln holds weight for y=ln

  // ---- phase 4: out[c] = sum_y A_bf16[y][c] * w[y], split across halves ----
  float a0 = 0.f;
  if (tid < 256) {
    #pragma unroll
    for (int y = 0; y < 32; ++y) {
      float wy = __shfl(wgt, y);    // literal lane -> v_readlane (SGPR)
      a0 = fmaf(bf2f(Abf[y * AST + tid]), wy, a0);
    }
  } else {
    const int c = tid - 256;
    #pragma unroll
    for (int y = 32; y < 64; ++y) {
      float wy = __shfl(wgt, y);
      a0 = fmaf(bf2f(Abf[y * AST + c]), wy, a0);
    }
    ph[c] = a0;
  }
  __syncthreads();
  if (tid < 256) out[(size_t)tok * 256 + tid] = a0 + ph[tid];
}

extern "C" void kernel_launch(void* const* d_in, const int* in_sizes, int n_in,
                              void* d_out, int out_size, void* d_ws, size_t ws_size,
                              hipStream_t stream) {
  const float* sampled = (const float*)d_in[0];
  const float* valid   = (const float*)d_in[1];
  const float* y_norm  = (const float*)d_in[2];
  const float* W1      = (const float*)d_in[3];   // [257,256]
  const float* b1      = (const float*)d_in[4];
  const float* W2      = (const float*)d_in[5];
  const float* b2      = (const float*)d_in[6];
  short* W1s = (short*)d_ws;                      // 128 KiB swizzled bf16 W1
  float* out = (float*)d_out;

  prep_w1<<<32, 256, 0, stream>>>(W1, W1s);
  agg_kernel<<<NTOK, 512, 0, stream>>>(sampled, valid, y_norm, W1, b1, W2, b2, W1s, out);
}